// Round 6
// baseline (2639.640 us; speedup 1.0000x reference)
//
#include <hip/hip_runtime.h>
#include <hip/hip_bf16.h>

// GatedLSTM: B=64, T=256, IN=512, H=1024. i-gate dead in reference -> dropped.
// Round 6: round-4 sentinel protocol kept, but (a) U weights in LDS (frees
// ~100 VGPRs), (b) all 32 A-fragment loads flat-issued -> 1 L2-miss RT
// instead of 8 serialized, (c) h published as full 64B lines via LDS
// transpose (kills 4x write-through RMW amplification).

typedef __attribute__((ext_vector_type(8))) short bfrag;   // 8 x bf16 (4 VGPR)
typedef __attribute__((ext_vector_type(4))) float f32x4;   // MFMA accumulator

__device__ __forceinline__ unsigned short f2b(float v) {
  __hip_bfloat16 h = __float2bfloat16(v);
  union { __hip_bfloat16 h; unsigned short u; } c; c.h = h; return c.u;
}
__device__ __forceinline__ float b2f(unsigned short u) {
  union { unsigned int i; float f; } c; c.i = ((unsigned int)u) << 16; return c.f;
}
__device__ __forceinline__ float sigm(float x) { return 1.0f / (1.0f + __expf(-x)); }
__device__ __forceinline__ float tanh_f(float x) {
  float e = __expf(2.0f * x);
  return (e - 1.0f) / (e + 1.0f);
}

// ---------------------------------------------------------------------------
// Phase 1: x-projections (unchanged). mlx[t][g][j][b] bf16.
// ---------------------------------------------------------------------------
__global__ __launch_bounds__(512, 2) void xproj_kernel(
    const float* __restrict__ inp,
    const float* __restrict__ Wf, const float* __restrict__ Wmf,
    const float* __restrict__ Wo, const float* __restrict__ Wmo,
    const float* __restrict__ Wc, const float* __restrict__ Wmc,
    unsigned short* __restrict__ mlx)
{
  __shared__ unsigned short Al[256 * 128];  // 64 KB, XOR-swizzled rows
  __shared__ unsigned short Bl[256 * 128];  // 64 KB

  const int tid = threadIdx.x;
  const int w = tid >> 6, l = tid & 63;
  const int c = l & 15, g4 = l >> 4;
  const int jc = blockIdx.x, gate = blockIdx.y, tq = blockIdx.z;
  const float* W  = (gate == 0) ? Wf  : (gate == 1) ? Wo  : Wc;
  const float* Wm = (gate == 0) ? Wmf : (gate == 1) ? Wmo : Wmc;
  const int j0 = jc * 128;

  f32x4 acc[2][16];
#pragma unroll
  for (int mi = 0; mi < 2; ++mi)
#pragma unroll
    for (int ni = 0; ni < 16; ++ni) acc[mi][ni] = (f32x4){0.f, 0.f, 0.f, 0.f};

  for (int kc = 0; kc < 4; ++kc) {
#pragma unroll
    for (int i = 0; i < 16; ++i) {
      int idx = tid + i * 512;      // 0..8191
      int row = idx >> 5;           // 0..255
      int xl  = idx & 31;           // 16B unit within 128-float chunk
      int b_ = row & 63, tl = row >> 6;
      const float4 va = *(const float4*)(inp + (size_t)(b_ * 256 + tq * 4 + tl) * 512 + kc * 128 + xl * 4);
      ushort4 pa;
      pa.x = f2b(va.x); pa.y = f2b(va.y); pa.z = f2b(va.z); pa.w = f2b(va.w);
      *(ushort4*)((char*)Al + ((row * 256 + xl * 8) ^ ((row & 7) << 4))) = pa;
      const float* src = (row < 128) ? (W + (size_t)(j0 + row) * 512)
                                     : (Wm + (size_t)(j0 + row - 128) * 512);
      const float4 vb = *(const float4*)(src + kc * 128 + xl * 4);
      ushort4 pb;
      pb.x = f2b(vb.x); pb.y = f2b(vb.y); pb.z = f2b(vb.z); pb.w = f2b(vb.w);
      *(ushort4*)((char*)Bl + ((row * 256 + xl * 8) ^ ((row & 7) << 4))) = pb;
    }
    __syncthreads();
#pragma unroll
    for (int ks = 0; ks < 4; ++ks) {
      const int koff = (ks * 32 + g4 * 8) * 2;
      bfrag af[2];
#pragma unroll
      for (int mi = 0; mi < 2; ++mi) {
        int row = w * 32 + mi * 16 + c;
        af[mi] = *(const bfrag*)((const char*)Al + ((row * 256 + koff) ^ ((row & 7) << 4)));
      }
#pragma unroll
      for (int ni = 0; ni < 16; ++ni) {
        int n = ni * 16 + c;
        bfrag bf = *(const bfrag*)((const char*)Bl + ((n * 256 + koff) ^ ((n & 7) << 4)));
#pragma unroll
        for (int mi = 0; mi < 2; ++mi)
          acc[mi][ni] = __builtin_amdgcn_mfma_f32_16x16x32_bf16(af[mi], bf, acc[mi][ni], 0, 0, 0);
      }
    }
    __syncthreads();
  }
#pragma unroll
  for (int mi = 0; mi < 2; ++mi) {
#pragma unroll
    for (int ni = 0; ni < 8; ++ni) {
      f32x4 xw = acc[mi][ni];
      f32x4 xm = acc[mi][ni + 8];
      ushort4 st;
      st.x = f2b(xw[0] * sigm(xm[0]));
      st.y = f2b(xw[1] * sigm(xm[1]));
      st.z = f2b(xw[2] * sigm(xm[2]));
      st.w = f2b(xw[3] * sigm(xm[3]));
      int row = w * 32 + mi * 16 + g4 * 4;
      int tl = row >> 6, b_ = row & 63;
      int j = j0 + ni * 16 + c;
      size_t addr = ((size_t)((tq * 4 + tl) * 3 + gate) * 1024 + j) * 64 + b_;
      *(ushort4*)(mlx + addr) = st;
    }
  }
}

// ---------------------------------------------------------------------------
// Phase 2: persistent recurrent kernel. 128 blocks x 256 threads, 1 block/CU
// (149 KB LDS). Block owns h-cols j0=8*bid..+8. U (48 rows x 1024 bf16) in
// LDS, XOR-swizzled. Per step per wave:
//   poll 32 producers' 4 wave-sentinels (8B agent loads) ->
//   flat-issue 32 cached A-frag 16B loads (af[8][4], ~1 RT total) ->
//   96 MFMAs with B ds_reads -> prep ds_write -> sync -> reduce+gates ->
//   hshare transpose -> sync -> 16 lanes/wave store full 64B lines (8B agent
//   atomics) -> vmcnt(0) -> per-wave sentinel.
// ---------------------------------------------------------------------------
__global__ __launch_bounds__(256, 1) void recur_kernel(
    const float* __restrict__ Uf, const float* __restrict__ Umf,
    const float* __restrict__ Uo, const float* __restrict__ Umo,
    const float* __restrict__ Uc, const float* __restrict__ Umc,
    const float* __restrict__ bfp, const float* __restrict__ bop,
    const float* __restrict__ bcp,
    const unsigned short* __restrict__ mlx,  // [256][3][1024][64] bf16
    unsigned short* __restrict__ hx,         // [257][128][64][8] bf16
    float* __restrict__ cfin,                // [1024][64] f32
    unsigned int* __restrict__ sent)         // [257][128][4]
{
  __shared__ unsigned short Blds[48 * 1024]; // 96 KB, XOR-swizzled
  __shared__ float prep[4 * 48 * 68];        // 52 KB partials [w][col][row]
  __shared__ unsigned int hshare[64 * 4];    // 1 KB  [b][w] packed h dwords

  // One-time L1+L2 invalidate: discards poison-epoch / cross-replay lines.
  __builtin_amdgcn_fence(__ATOMIC_ACQUIRE, "agent");

  const int tid = threadIdx.x;
  const int bid = blockIdx.x;
  const int w = tid >> 6, l = tid & 63;
  const int c = l & 15, g4 = l >> 4;
  const int j0 = bid * 8;

  // ---- one-time U stage into LDS (rows n = mat*8 + col, 6 mats) --------
  {
    const float* mats[6] = {Uf, Umf, Uo, Umo, Uc, Umc};
    const int rbase = tid >> 4;   // 0..15
    const int sub = tid & 15;     // 0..15
#pragma unroll
    for (int rep = 0; rep < 3; ++rep) {
      int r = rep * 16 + rbase;
      const float* src = mats[r >> 3] + (size_t)(j0 + (r & 7)) * 1024;
#pragma unroll
      for (int i = 0; i < 16; ++i) {
        int k = sub * 64 + i * 4;
        float4 v = *(const float4*)(src + k);
        ushort4 p;
        p.x = f2b(v.x); p.y = f2b(v.y); p.z = f2b(v.z); p.w = f2b(v.w);
        *(ushort4*)((char*)Blds + (((r * 1024 + k) * 2) ^ ((r & 7) << 4))) = p;
      }
    }
  }

  const int bb = l;               // elementwise: b = lane, cols cl0 = 2w
  const int cl0 = w * 2;
  float bias[2][3], cr[2] = {0.f, 0.f};
#pragma unroll
  for (int q = 0; q < 2; ++q) {
    bias[q][0] = bfp[j0 + cl0 + q];
    bias[q][1] = bop[j0 + cl0 + q];
    bias[q][2] = bcp[j0 + cl0 + q];
  }
  // per-lane B read bases: row n = nt*16+c, byte = n*2048 + ((2k) ^ ((n&7)<<4))
  const int kb0 = (w * 256 + g4 * 8) * 2;   // per-lane k byte base
  __syncthreads();

  for (int t = 0; t < 256; ++t) {
    // mlx for THIS step: issue before the poll; HBM latency hides under wait
    float mfv[2], mov[2], mcv[2];
    {
      size_t mb = (size_t)t * 3 * 65536 + (size_t)(j0 + cl0) * 64 + bb;
#pragma unroll
      for (int q = 0; q < 2; ++q) {
        mfv[q] = b2f(mlx[mb + q * 64]);
        mov[q] = b2f(mlx[mb + 65536 + q * 64]);
        mcv[q] = b2f(mlx[mb + 2 * 65536 + q * 64]);
      }
    }

    // ---- per-wave sentinel poll: producers 32w..32w+31, all 4 waves ----
    if (t > 0) {
      const unsigned long long* sp =
          (const unsigned long long*)(sent + (size_t)t * 512 + w * 128 + 2 * l);
      while (true) {
        unsigned long long v = __hip_atomic_load(sp, __ATOMIC_RELAXED, __HIP_MEMORY_SCOPE_AGENT);
        if (__all(v == 0x0000000100000001ULL)) break;
      }
      __builtin_amdgcn_sched_barrier(0);
      asm volatile("" ::: "memory");   // keep h loads below the poll
    }

    // ---- flat-issue ALL 32 A-fragment loads (cached, ~1 RT total) ------
    bfrag af[8][4];
#pragma unroll
    for (int ks = 0; ks < 8; ++ks) {
      const int kb = w * 32 + ks * 4 + g4;   // wave-private chunk ids
      const unsigned short* rp = hx + (((size_t)t * 128 + kb) * 64 + c) * 8;
#pragma unroll
      for (int mi = 0; mi < 4; ++mi)
        af[ks][mi] = *(const bfrag*)(rp + mi * 16 * 8);
    }

    f32x4 acc[4][3];
#pragma unroll
    for (int mi = 0; mi < 4; ++mi)
#pragma unroll
      for (int nt = 0; nt < 3; ++nt) acc[mi][nt] = (f32x4){0.f, 0.f, 0.f, 0.f};

#pragma unroll
    for (int ks = 0; ks < 8; ++ks) {
      const int kb2 = kb0 + ks * 64;
      bfrag bfr[3];
#pragma unroll
      for (int nt = 0; nt < 3; ++nt) {
        const int n = nt * 16 + c;
        bfr[nt] = *(const bfrag*)((const char*)Blds + (n * 2048 + (kb2 ^ ((n & 7) << 4))));
      }
#pragma unroll
      for (int mi = 0; mi < 4; ++mi)
#pragma unroll
        for (int nt = 0; nt < 3; ++nt)
          acc[mi][nt] = __builtin_amdgcn_mfma_f32_16x16x32_bf16(af[ks][mi], bfr[nt], acc[mi][nt], 0, 0, 0);
    }

#pragma unroll
    for (int mi = 0; mi < 4; ++mi)
#pragma unroll
      for (int nt = 0; nt < 3; ++nt) {
        int col = nt * 16 + c;
        *(f32x4*)&prep[(w * 48 + col) * 68 + mi * 16 + g4 * 4] = acc[mi][nt];
      }
    __syncthreads();

    unsigned int pack = 0;
#pragma unroll
    for (int q = 0; q < 2; ++q) {
      const int cl = cl0 + q;
      float s[6];
#pragma unroll
      for (int m = 0; m < 6; ++m) {
        const int col = m * 8 + cl;
        s[m] = prep[col * 68 + bb] + prep[(48 + col) * 68 + bb] +
               prep[(96 + col) * 68 + bb] + prep[(144 + col) * 68 + bb];
      }
      float fg = sigm(mfv[q] + sigm(s[1]) * s[0] + bias[q][0]);
      float og = sigm(mov[q] + sigm(s[3]) * s[2] + bias[q][1]);
      float cd = tanh_f(mcv[q] + sigm(s[5]) * s[4] + bias[q][2]);
      cr[q] = fg * cr[q] + cd;
      float hv = og * cr[q];
      pack |= (unsigned int)f2b(hv) << (16 * q);
      if (t == 255) cfin[(size_t)(j0 + cl) * 64 + bb] = cr[q];
    }

    // ---- transpose through LDS, then full-line publish -----------------
    hshare[bb * 4 + w] = pack;       // [b][w]: w holds cols 2w..2w+1
    __syncthreads();                 // also protects prep reuse next step

    if (l < 16) {
      const int row = w * 16 + l;    // this wave publishes b = 16w..16w+15
      const uint4 hv4 = *(const uint4*)&hshare[row * 4];   // 16B = 8 cols
      unsigned long long q0 = ((unsigned long long)hv4.y << 32) | hv4.x;
      unsigned long long q1 = ((unsigned long long)hv4.w << 32) | hv4.z;
      unsigned long long* dst =
          (unsigned long long*)(hx + ((((size_t)(t + 1) * 128 + bid) * 64 + row) * 8));
      __hip_atomic_store(dst,     q0, __ATOMIC_RELAXED, __HIP_MEMORY_SCOPE_AGENT);
      __hip_atomic_store(dst + 1, q1, __ATOMIC_RELAXED, __HIP_MEMORY_SCOPE_AGENT);
    }
    // per-WAVE drain: this wave's h lines acked at MALL, then its sentinel
    asm volatile("s_waitcnt vmcnt(0)" ::: "memory");
    if (l == 0)
      __hip_atomic_store(&sent[(size_t)(t + 1) * 512 + bid * 4 + w], 1u,
                         __ATOMIC_RELAXED, __HIP_MEMORY_SCOPE_AGENT);
  }
}

// ---------------------------------------------------------------------------
// Phase 3: hx chunks -> out [b][t][j] f32 (streaming cast)
// ---------------------------------------------------------------------------
__global__ __launch_bounds__(128) void histcast_kernel(
    const unsigned short* __restrict__ hx, float* __restrict__ out)
{
  const int b = blockIdx.x >> 8, t = blockIdx.x & 255;
  const int j = threadIdx.x * 8;
  const unsigned short* src = hx + (((size_t)(t + 1) * 128 + (j >> 3)) * 64 + b) * 8;
  float* dst = out + ((size_t)b * 256 + t) * 1024 + j;
  ushort4 v0 = *(const ushort4*)(src);
  ushort4 v1 = *(const ushort4*)(src + 4);
  float4 o0, o1;
  o0.x = b2f(v0.x); o0.y = b2f(v0.y); o0.z = b2f(v0.z); o0.w = b2f(v0.w);
  o1.x = b2f(v1.x); o1.y = b2f(v1.y); o1.z = b2f(v1.z); o1.w = b2f(v1.w);
  *(float4*)(dst) = o0;
  *(float4*)(dst + 4) = o1;
}

__global__ __launch_bounds__(256) void finals_kernel(
    const unsigned short* __restrict__ hx, const float* __restrict__ cfin,
    float* __restrict__ out)
{
  int tid = blockIdx.x * 256 + threadIdx.x;  // 0..65535 = b*1024 + j
  int b = tid >> 10, j = tid & 1023;
  out[16777216 + tid]         = b2f(hx[(((size_t)256 * 128 + (j >> 3)) * 64 + b) * 8 + (j & 7)]);
  out[16777216 + 65536 + tid] = cfin[(size_t)j * 64 + b];
}

// ---------------------------------------------------------------------------
extern "C" void kernel_launch(void* const* d_in, const int* in_sizes, int n_in,
                              void* d_out, int out_size, void* d_ws, size_t ws_size,
                              hipStream_t stream)
{
  const float* input = (const float*)d_in[0];
  const float* W_f  = (const float*)d_in[1];
  const float* Wm_f = (const float*)d_in[2];
  const float* U_f  = (const float*)d_in[3];
  const float* Um_f = (const float*)d_in[4];
  const float* b_f  = (const float*)d_in[5];
  const float* W_o  = (const float*)d_in[11];
  const float* Wm_o = (const float*)d_in[12];
  const float* U_o  = (const float*)d_in[13];
  const float* Um_o = (const float*)d_in[14];
  const float* b_o  = (const float*)d_in[15];
  const float* W_c  = (const float*)d_in[16];
  const float* Wm_c = (const float*)d_in[17];
  const float* U_c  = (const float*)d_in[18];
  const float* Um_c = (const float*)d_in[19];
  const float* b_c  = (const float*)d_in[20];

  char* ws = (char*)d_ws;
  size_t off = 0;
  unsigned short* mlx = (unsigned short*)(ws + off); off += (size_t)256 * 3 * 1024 * 64 * 2; // 100.7 MB
  unsigned short* hx  = (unsigned short*)(ws + off); off += (size_t)257 * 128 * 64 * 8 * 2;  //  33.7 MB
  float* cfin = (float*)(ws + off);                  off += (size_t)1024 * 64 * 4;
  unsigned int* sent = (unsigned int*)(ws + off);    off += (size_t)257 * 512 * 4;           // 526 KB
  if (off > ws_size) return;  // insufficient workspace: bail cleanly

  hipMemsetAsync(hx, 0, 131072, stream);                  // h0 = 0 (chunk step 0)
  hipMemsetAsync(sent, 0, (size_t)257 * 512 * 4, stream); // sentinels

  xproj_kernel<<<dim3(8, 3, 64), 512, 0, stream>>>(input, W_f, Wm_f, W_o, Wm_o, W_c, Wm_c, mlx);
  recur_kernel<<<128, 256, 0, stream>>>(U_f, Um_f, U_o, Um_o, U_c, Um_c,
                                        b_f, b_o, b_c, mlx, hx, cfin, sent);
  histcast_kernel<<<16384, 128, 0, stream>>>(hx, (float*)d_out);
  finals_kernel<<<256, 256, 0, stream>>>(hx, cfin, (float*)d_out);
}